// Round 3
// baseline (191.070 us; speedup 1.0000x reference)
//
#include <hip/hip_runtime.h>
#include <hip/hip_bf16.h>
#include <math.h>

// ---------------------------------------------------------------------------
// HybridClassifier, fully fused:
//   K0: w1 -> bf16 [128][800] (zero-padded)
//   K1 (mega): per block = 16 batch rows:
//     phase A: quantum filter -> feats bf16 in LDS [16][808]
//     phase B: fc1 = relu(feats @ w1B^T + b1) via 16x16x32 bf16 MFMA -> LDS
//     phase D: fc2+relu, fc3, analytic head -> out
// ---------------------------------------------------------------------------

#define BATCH   8192
#define NPATCH  196
#define KPAD    800
#define FLD     808     // feats LDS row stride (halves): 2-way banks max
#define H1LD    132     // h1 LDS row stride (words): 2-way banks max

typedef __attribute__((ext_vector_type(8))) short bfrag;
typedef __attribute__((ext_vector_type(4))) float f32x4;
typedef __attribute__((ext_vector_type(2))) float f32x2;

static __device__ __forceinline__ unsigned short f2bf(float f) {
    __hip_bfloat16 h = __float2bfloat16(f);
    return __builtin_bit_cast(unsigned short, h);
}

// ===========================================================================
// K0: w1 (fp32 [120][784]) -> bf16 [128][800], zero-padded.
// ===========================================================================
__global__ __launch_bounds__(256) void w1prep_kernel(
    const float* __restrict__ w1, unsigned short* __restrict__ w1B)
{
    int t = blockIdx.x * 256 + threadIdx.x;
    if (t >= 128 * KPAD) return;
    int n = t / KPAD;
    int k = t - n * KPAD;
    float v = (n < 120 && k < 784) ? w1[n * 784 + k] : 0.f;
    w1B[t] = f2bf(v);
}

// ===========================================================================
// K1: mega kernel. Grid 512 x 256 threads; block handles rows m0..m0+15.
// ===========================================================================
__global__ __launch_bounds__(256) void mega_kernel(
    const float* __restrict__ x, const float* __restrict__ U,
    const unsigned short* __restrict__ w1B,
    const float* __restrict__ b1,
    const float* __restrict__ w2, const float* __restrict__ b2,
    const float* __restrict__ w3, const float* __restrict__ b3,
    float* __restrict__ out)
{
    __shared__ unsigned short featsL[16 * FLD];  // 25856 B
    __shared__ float h1L[16 * H1LD];             //  8448 B
    __shared__ float h2L[16 * 84];               //  5376 B

    const int tid = threadIdx.x;
    const int m0  = blockIdx.x * 16;

    // ---- zero the K-pad tail cols 784..799 of each feats row ----
    {
        int r = tid >> 4;
        int c = 784 + (tid & 15);
        featsL[r * FLD + c] = 0;
    }

    // ---- phase A: quantum filter, 16 rows x 196 patches = 3136 items ----
    const f32x2* U2 = reinterpret_cast<const f32x2*>(U);   // [16][8] f32x2
    for (int e = tid; e < 16 * NPATCH; e += 256) {
        int r = e / NPATCH;
        int p = e - r * NPATCH;
        int pr = p / 14;
        int pc = p - pr * 14;
        const float* xr = x + (size_t)(m0 + r) * 784 + pr * 56 + pc * 2;
        f32x2 xa = *reinterpret_cast<const f32x2*>(xr);
        f32x2 xb = *reinterpret_cast<const f32x2*>(xr + 28);

        float s0, c0, s1, c1, s2, c2, s3, c3;
        __sincosf(0.5f * xa.x, &s0, &c0);
        __sincosf(0.5f * xa.y, &s1, &c1);
        __sincosf(0.5f * xb.x, &s2, &c2);
        __sincosf(0.5f * xb.y, &s3, &c3);

        float t01[4] = {c0 * c1, c0 * s1, s0 * c1, s0 * s1};
        f32x2 t23p0 = {c2 * c3, c2 * s3};
        f32x2 t23p1 = {s2 * c3, s2 * s3};

        // psi2[j] = psi[2j..2j+1]; psi[i] = t01[i>>2]*t23[i&3]
        f32x2 psi2[8];
#pragma unroll
        for (int j = 0; j < 8; ++j)
            psi2[j] = ((j & 1) ? t23p1 : t23p0) * t01[j >> 1];

        // phi = U @ psi (pk-fma), q2[j] = phi2^2
        f32x2 q2[8];
#pragma unroll
        for (int jq = 0; jq < 8; ++jq) {
            f32x2 accA = U2[(2 * jq) * 8] * psi2[0];
            f32x2 accB = U2[(2 * jq + 1) * 8] * psi2[0];
#pragma unroll
            for (int j = 1; j < 8; ++j) {
                accA = U2[(2 * jq) * 8 + j] * psi2[j] + accA;
                accB = U2[(2 * jq + 1) * 8 + j] * psi2[j] + accB;
            }
            float pa = accA.x + accA.y;
            float pb = accB.x + accB.y;
            f32x2 ph = {pa, pb};
            q2[jq] = ph * ph;
        }

        // sign reductions: i = 2j+d; bit3=j>=4, bit2=j&2, bit1=j&1, bit0=d
        f32x2 s01 = q2[0] + q2[1], s23 = q2[2] + q2[3];
        f32x2 s45 = q2[4] + q2[5], s67 = q2[6] + q2[7];
        f32x2 e0 = s01 + s23, e1 = s45 + s67;
        f32x2 t0 = s01 - s23, t1 = s45 - s67;
        f32x2 g  = (q2[0] - q2[1]) + (q2[2] - q2[3])
                 + (q2[4] - q2[5]) + (q2[6] - q2[7]);
        f32x2 F  = e0 + e1;
        float m0v = (e0.x + e0.y) - (e1.x + e1.y);
        float m1v = (t0.x + t0.y) + (t1.x + t1.y);
        float m2v = g.x + g.y;
        float m3v = F.x - F.y;

        ushort4 o;
        o.x = f2bf(m0v); o.y = f2bf(m1v); o.z = f2bf(m2v); o.w = f2bf(m3v);
        *reinterpret_cast<ushort4*>(&featsL[r * FLD + p * 4]) = o;
    }
    __syncthreads();

    // ---- phase B: fc1 MFMA. wave w -> cols [w*32, w*32+32) ----
    {
        const int wave = tid >> 6;
        const int lane = tid & 63;
        const int row  = lane & 15;
        const int grp  = lane >> 4;

        const unsigned short* fA = &featsL[row * FLD + grp * 8];
        const unsigned short* bp0 =
            w1B + (size_t)(wave * 32 + row) * KPAD + grp * 8;
        const unsigned short* bp1 = bp0 + 16 * KPAD;

        f32x4 acc0 = {}, acc1 = {};
        for (int k0 = 0; k0 < KPAD; k0 += 32) {
            bfrag a  = *reinterpret_cast<const bfrag*>(fA + k0);
            bfrag b0 = *reinterpret_cast<const bfrag*>(bp0 + k0);
            bfrag b1f = *reinterpret_cast<const bfrag*>(bp1 + k0);
            acc0 = __builtin_amdgcn_mfma_f32_16x16x32_bf16(a, b0, acc0, 0, 0, 0);
            acc1 = __builtin_amdgcn_mfma_f32_16x16x32_bf16(a, b1f, acc1, 0, 0, 0);
        }

        f32x4 accs[2] = {acc0, acc1};
#pragma unroll
        for (int nj = 0; nj < 2; ++nj) {
            int col = wave * 32 + nj * 16 + row;
            if (col < 120) {
                float bias = b1[col];
#pragma unroll
                for (int rr = 0; rr < 4; ++rr) {
                    float v = accs[nj][rr] + bias;
                    h1L[(grp * 4 + rr) * H1LD + col] = fmaxf(v, 0.f);
                }
            }
        }
    }
    __syncthreads();

    // ---- phase D: fc2+relu (16 x 84), 336 col-quad items ----
    for (int e = tid; e < 16 * 21; e += 256) {
        int r  = e / 21;
        int nq = e - r * 21;
        int n0 = nq * 4;
        float4 bias = *reinterpret_cast<const float4*>(b2 + n0);
        float accv[4] = {bias.x, bias.y, bias.z, bias.w};
#pragma unroll
        for (int kq = 0; kq < 30; ++kq) {
            float4 a = *reinterpret_cast<const float4*>(&h1L[r * H1LD + kq * 4]);
#pragma unroll
            for (int nn = 0; nn < 4; ++nn) {
                const float4 wv = *reinterpret_cast<const float4*>(
                    w2 + (size_t)(n0 + nn) * 120 + kq * 4);
                accv[nn] = fmaf(a.x, wv.x, accv[nn]);
                accv[nn] = fmaf(a.y, wv.y, accv[nn]);
                accv[nn] = fmaf(a.z, wv.z, accv[nn]);
                accv[nn] = fmaf(a.w, wv.w, accv[nn]);
            }
        }
        float4 o;
        o.x = fmaxf(accv[0], 0.f);
        o.y = fmaxf(accv[1], 0.f);
        o.z = fmaxf(accv[2], 0.f);
        o.w = fmaxf(accv[3], 0.f);
        *reinterpret_cast<float4*>(&h2L[r * 84 + n0]) = o;
    }
    __syncthreads();

    // ---- fc3 + head, one thread per row ----
    if (tid < 16) {
        int r = tid;
        float acc = b3[0];
#pragma unroll
        for (int kq = 0; kq < 21; ++kq) {
            float4 a  = *reinterpret_cast<const float4*>(&h2L[r * 84 + kq * 4]);
            float4 wv = *reinterpret_cast<const float4*>(w3 + kq * 4);
            acc = fmaf(a.x, wv.x, acc);
            acc = fmaf(a.y, wv.y, acc);
            acc = fmaf(a.z, wv.z, acc);
            acc = fmaf(a.w, wv.w, acc);
        }
        float ev = 0.5f * (1.0f + __sinf(acc));
        float pp = 1.0f / (1.0f + __expf(-ev));
        out[m0 + r]         = pp;
        out[BATCH + m0 + r] = 1.0f - pp;
    }
}

// ===========================================================================
extern "C" void kernel_launch(void* const* d_in, const int* in_sizes, int n_in,
                              void* d_out, int out_size, void* d_ws, size_t ws_size,
                              hipStream_t stream)
{
    (void)in_sizes; (void)n_in; (void)out_size; (void)ws_size;
    const float* x  = (const float*)d_in[0];
    const float* U  = (const float*)d_in[1];
    const float* w1 = (const float*)d_in[2];
    const float* b1 = (const float*)d_in[3];
    const float* w2 = (const float*)d_in[4];
    const float* b2 = (const float*)d_in[5];
    const float* w3 = (const float*)d_in[6];
    const float* b3 = (const float*)d_in[7];
    float* out = (float*)d_out;

    unsigned short* w1B = (unsigned short*)d_ws;   // 128*800 bf16 = 205 KB

    w1prep_kernel<<<dim3((128 * KPAD + 255) / 256), dim3(256), 0, stream>>>(w1, w1B);
    mega_kernel<<<dim3(BATCH / 16), dim3(256), 0, stream>>>(
        x, U, w1B, b1, w2, b2, w3, b3, out);
}

// Round 4
// 138.287 us; speedup vs baseline: 1.3817x; 1.3817x over previous
//
#include <hip/hip_runtime.h>
#include <hip/hip_bf16.h>
#include <math.h>

// ---------------------------------------------------------------------------
// HybridClassifier, fused, MFMA quantum filter:
//   K0: w1 -> bf16 [128][800] (zero-padded)
//   K1 (mega), 8 batch rows per block, grid 1024:
//     phase A: psi (VALU trig) -> wave-private LDS -> phi^T = U*psi^T via
//              16x16x32 bf16 MFMA (U in regs, loaded once) -> WHT sign-reduce
//              (f32 shfl_xor) -> feats bf16 in LDS [8][808]
//     phase B: fc1 = relu(feats @ w1B^T + b1) via MFMA -> h1 LDS
//     phase D: fc2+relu, fc3, analytic head -> out
// ---------------------------------------------------------------------------

#define BATCH   8192
#define NPATCH  196
#define ROWS    8
#define NITEMS  (ROWS * NPATCH)   // 1568
#define KPAD    800
#define FLD     808
#define H1LD    132

typedef __attribute__((ext_vector_type(8))) short bfrag;
typedef __attribute__((ext_vector_type(4))) float f32x4;

static __device__ __forceinline__ unsigned short f2bf(float f) {
    __hip_bfloat16 h = __float2bfloat16(f);
    return __builtin_bit_cast(unsigned short, h);
}
static __device__ __forceinline__ unsigned int pkbf(float lo, float hi) {
    return ((unsigned int)f2bf(hi) << 16) | (unsigned int)f2bf(lo);
}

// ===========================================================================
// K0: w1 (fp32 [120][784]) -> bf16 [128][800], zero-padded.
// ===========================================================================
__global__ __launch_bounds__(256) void w1prep_kernel(
    const float* __restrict__ w1, unsigned short* __restrict__ w1B)
{
    int t = blockIdx.x * 256 + threadIdx.x;
    if (t >= 128 * KPAD) return;
    int n = t / KPAD;
    int k = t - n * KPAD;
    float v = (n < 120 && k < 784) ? w1[n * 784 + k] : 0.f;
    w1B[t] = f2bf(v);
}

// ===========================================================================
// K1: mega kernel. Grid 1024 x 256 threads; block = batch rows m0..m0+7.
// ===========================================================================
__global__ __launch_bounds__(256, 4) void mega_kernel(
    const float* __restrict__ x, const float* __restrict__ U,
    const unsigned short* __restrict__ w1B,
    const float* __restrict__ b1,
    const float* __restrict__ w2, const float* __restrict__ b2,
    const float* __restrict__ w3, const float* __restrict__ b3,
    float* __restrict__ out)
{
    __shared__ __align__(16) unsigned short featsL[ROWS * FLD];  // 12928 B
    __shared__ __align__(16) unsigned short psiL[4][64][40];     // 20480 B
    __shared__ __align__(16) float h1L[ROWS * H1LD];             //  4224 B
    __shared__ __align__(16) float h2L[ROWS * 84];               //  2688 B

    const int tid  = threadIdx.x;
    const int lane = tid & 63;
    const int wv   = tid >> 6;
    const int lrow = lane & 15;
    const int lgrp = lane >> 4;
    const int m0   = blockIdx.x * ROWS;

    // zero feats K-pad tail (cols 784..799)
    if (tid < ROWS * 16)
        featsL[(tid >> 4) * FLD + 784 + (tid & 15)] = 0;

    // zero psi pad region (k = 16..31), written once, wave-private
    {
        uint4 z = {0u, 0u, 0u, 0u};
        *reinterpret_cast<uint4*>(&psiL[wv][lane][16]) = z;
        *reinterpret_cast<uint4*>(&psiL[wv][lane][24]) = z;
    }

    // U as MFMA A-frag, loaded ONCE: A[row=lrow][k=8*lgrp+j], zero for k>=16
    bfrag Uf;
    {
        union { bfrag f; unsigned int u[4]; } uu;
        if (lgrp < 2) {
            float4 a = *reinterpret_cast<const float4*>(U + lrow * 16 + lgrp * 8);
            float4 b = *reinterpret_cast<const float4*>(U + lrow * 16 + lgrp * 8 + 4);
            uu.u[0] = pkbf(a.x, a.y); uu.u[1] = pkbf(a.z, a.w);
            uu.u[2] = pkbf(b.x, b.y); uu.u[3] = pkbf(b.z, b.w);
        } else {
            uu.u[0] = uu.u[1] = uu.u[2] = uu.u[3] = 0u;
        }
        Uf = uu.f;
    }

    // ---- phase A: 25 chunks of 64 items, round-robined over 4 waves ----
    for (int c = wv; c < (NITEMS + 63) / 64; c += 4) {
        int item = c * 64 + lane;
        int it   = item < NITEMS - 1 ? item : NITEMS - 1;   // clamp tail
        int r  = it / NPATCH;
        int p  = it - r * NPATCH;
        int pr = p / 14;
        int pc = p - pr * 14;
        const float* xr = x + (size_t)(m0 + r) * 784 + pr * 56 + pc * 2;
        float2 xa = *reinterpret_cast<const float2*>(xr);
        float2 xb = *reinterpret_cast<const float2*>(xr + 28);

        float s0 = __sinf(0.5f * xa.x), c0 = __cosf(0.5f * xa.x);
        float s1 = __sinf(0.5f * xa.y), c1 = __cosf(0.5f * xa.y);
        float s2 = __sinf(0.5f * xb.x), c2 = __cosf(0.5f * xb.x);
        float s3 = __sinf(0.5f * xb.y), c3 = __cosf(0.5f * xb.y);

        float t01[4] = {c0 * c1, c0 * s1, s0 * c1, s0 * s1};
        float t23[4] = {c2 * c3, c2 * s3, s2 * c3, s2 * s3};

        unsigned int pw[8];
#pragma unroll
        for (int q = 0; q < 8; ++q) {
            float plo = t01[(2 * q) >> 2]     * t23[(2 * q) & 3];
            float phv = t01[(2 * q + 1) >> 2] * t23[(2 * q + 1) & 3];
            pw[q] = pkbf(plo, phv);
        }
        *reinterpret_cast<uint4*>(&psiL[wv][lane][0]) =
            make_uint4(pw[0], pw[1], pw[2], pw[3]);
        *reinterpret_cast<uint4*>(&psiL[wv][lane][8]) =
            make_uint4(pw[4], pw[5], pw[6], pw[7]);

        // 4 sub-tiles of 16 items: phi^T = U * psi^T, then WHT sign-reduce
#pragma unroll
        for (int sub = 0; sub < 4; ++sub) {
            bfrag Bf = *reinterpret_cast<const bfrag*>(
                &psiL[wv][sub * 16 + lrow][lgrp * 8]);
            f32x4 dz = {0.f, 0.f, 0.f, 0.f};
            f32x4 d = __builtin_amdgcn_mfma_f32_16x16x32_bf16(Uf, Bf, dz, 0, 0, 0);
            // lane: phi[i = 4*lgrp + reg][item = sub*16 + lrow]
            float q0 = d[0] * d[0], q1 = d[1] * d[1];
            float q2 = d[2] * d[2], q3 = d[3] * d[3];
            float sAll = (q0 + q1) + (q2 + q3);        // for w0, w1 (bits of lgrp)
            float uu2  = (q0 + q1) - (q2 + q3);        // w2: bit1 = reg>>1
            float vv2  = (q0 - q1) + (q2 - q3);        // w3: bit0 = reg&1
            float t    = __shfl_xor(sAll, 16);
            float Aa   = sAll + t;
            float Bb   = (lane & 16) ? (t - sAll) : (sAll - t);
            t = __shfl_xor(Aa, 32);
            float mw0 = (lane & 32) ? (t - Aa) : (Aa - t);   // sign by bit3
            float mw1 = Bb + __shfl_xor(Bb, 32);             // sign by bit2
            float u16 = uu2 + __shfl_xor(uu2, 16);
            float mw2 = u16 + __shfl_xor(u16, 32);
            float v16 = vv2 + __shfl_xor(vv2, 16);
            float mw3 = v16 + __shfl_xor(v16, 32);

            int item16 = c * 64 + sub * 16 + lrow;
            if (lgrp == 0 && item16 < NITEMS) {
                int rr = item16 / NPATCH;
                int pp = item16 - rr * NPATCH;
                ushort4 o;
                o.x = f2bf(mw0); o.y = f2bf(mw1);
                o.z = f2bf(mw2); o.w = f2bf(mw3);
                *reinterpret_cast<ushort4*>(&featsL[rr * FLD + pp * 4]) = o;
            }
        }
    }
    __syncthreads();

    // ---- phase B: fc1 MFMA. wave wv -> cols [wv*32, wv*32+32) ----
    {
        const unsigned short* fA = &featsL[(lrow & 7) * FLD + lgrp * 8];
        const unsigned short* bp0 =
            w1B + (size_t)(wv * 32 + lrow) * KPAD + lgrp * 8;
        const unsigned short* bp1 = bp0 + 16 * KPAD;

        f32x4 acc0 = {}, acc1 = {};
        for (int k0 = 0; k0 < KPAD; k0 += 32) {
            bfrag a   = *reinterpret_cast<const bfrag*>(fA + k0);
            bfrag b0  = *reinterpret_cast<const bfrag*>(bp0 + k0);
            bfrag b1f = *reinterpret_cast<const bfrag*>(bp1 + k0);
            acc0 = __builtin_amdgcn_mfma_f32_16x16x32_bf16(a, b0, acc0, 0, 0, 0);
            acc1 = __builtin_amdgcn_mfma_f32_16x16x32_bf16(a, b1f, acc1, 0, 0, 0);
        }
        f32x4 accs[2] = {acc0, acc1};
#pragma unroll
        for (int nj = 0; nj < 2; ++nj) {
            int col = wv * 32 + nj * 16 + lrow;
            if (col < 120) {
                float bias = b1[col];
#pragma unroll
                for (int rr2 = 0; rr2 < 4; ++rr2) {
                    int row = lgrp * 4 + rr2;   // D rows 8-15 duplicate 0-7
                    if (row < ROWS)
                        h1L[row * H1LD + col] =
                            fmaxf(accs[nj][rr2] + bias, 0.f);
                }
            }
        }
    }
    __syncthreads();

    // ---- phase D: fc2+relu (8 x 84 -> 168 col-quad items) ----
    for (int e = tid; e < ROWS * 21; e += 256) {
        int r  = e / 21;
        int nq = e - r * 21;
        int n0 = nq * 4;
        float4 bias = *reinterpret_cast<const float4*>(b2 + n0);
        float accv[4] = {bias.x, bias.y, bias.z, bias.w};
#pragma unroll
        for (int kq = 0; kq < 30; ++kq) {
            float4 a = *reinterpret_cast<const float4*>(&h1L[r * H1LD + kq * 4]);
#pragma unroll
            for (int nn = 0; nn < 4; ++nn) {
                const float4 wvv = *reinterpret_cast<const float4*>(
                    w2 + (size_t)(n0 + nn) * 120 + kq * 4);
                accv[nn] = fmaf(a.x, wvv.x, accv[nn]);
                accv[nn] = fmaf(a.y, wvv.y, accv[nn]);
                accv[nn] = fmaf(a.z, wvv.z, accv[nn]);
                accv[nn] = fmaf(a.w, wvv.w, accv[nn]);
            }
        }
        float4 o;
        o.x = fmaxf(accv[0], 0.f);
        o.y = fmaxf(accv[1], 0.f);
        o.z = fmaxf(accv[2], 0.f);
        o.w = fmaxf(accv[3], 0.f);
        *reinterpret_cast<float4*>(&h2L[r * 84 + n0]) = o;
    }
    __syncthreads();

    // ---- fc3 + head, one thread per row ----
    if (tid < ROWS) {
        int r = tid;
        float acc = b3[0];
#pragma unroll
        for (int kq = 0; kq < 21; ++kq) {
            float4 a   = *reinterpret_cast<const float4*>(&h2L[r * 84 + kq * 4]);
            float4 wvv = *reinterpret_cast<const float4*>(w3 + kq * 4);
            acc = fmaf(a.x, wvv.x, acc);
            acc = fmaf(a.y, wvv.y, acc);
            acc = fmaf(a.z, wvv.z, acc);
            acc = fmaf(a.w, wvv.w, acc);
        }
        float ev = 0.5f * (1.0f + __sinf(acc));
        float pp = 1.0f / (1.0f + __expf(-ev));
        out[m0 + r]         = pp;
        out[BATCH + m0 + r] = 1.0f - pp;
    }
}

// ===========================================================================
extern "C" void kernel_launch(void* const* d_in, const int* in_sizes, int n_in,
                              void* d_out, int out_size, void* d_ws, size_t ws_size,
                              hipStream_t stream)
{
    (void)in_sizes; (void)n_in; (void)out_size; (void)ws_size;
    const float* x  = (const float*)d_in[0];
    const float* U  = (const float*)d_in[1];
    const float* w1 = (const float*)d_in[2];
    const float* b1 = (const float*)d_in[3];
    const float* w2 = (const float*)d_in[4];
    const float* b2 = (const float*)d_in[5];
    const float* w3 = (const float*)d_in[6];
    const float* b3 = (const float*)d_in[7];
    float* out = (float*)d_out;

    unsigned short* w1B = (unsigned short*)d_ws;   // 128*800 bf16 = 205 KB

    w1prep_kernel<<<dim3((128 * KPAD + 255) / 256), dim3(256), 0, stream>>>(w1, w1B);
    mega_kernel<<<dim3(BATCH / ROWS), dim3(256), 0, stream>>>(
        x, U, w1B, b1, w2, b2, w3, b3, out);
}